// Round 1
// baseline (292.806 us; speedup 1.0000x reference)
//
#include <hip/hip_runtime.h>

// Problem constants
constexpr int Bz  = 8;
constexpr int Lz  = 512;
constexpr int Hz  = 256;
constexpr int H2z = 512;
constexpr int Vz  = 32000;
constexpr int Mz  = Bz * Lz;      // 4096 tokens
constexpr float CF = 0.05f;       // 1 - ALPHA

// ---------------------------------------------------------------------------
// GEMM1: y1[4096,512] = relu(embed[seq][4096,256] @ W1[256,512] + b1)
// 64x64 tile, BK=16, 256 threads, 4x4 per thread, fp32.
// ---------------------------------------------------------------------------
__global__ __launch_bounds__(256) void k_gemm1(
    const int* __restrict__ seq, const float* __restrict__ embed,
    const float* __restrict__ W1, const float* __restrict__ b1,
    float* __restrict__ y1)
{
  __shared__ float As[16][68];   // +4 pad: kills bank conflicts, keeps 16B align
  __shared__ float Bs[16][68];
  const int tid = threadIdx.x;
  const int n0 = blockIdx.x * 64, m0 = blockIdx.y * 64;
  const int tx = tid & 15, ty = tid >> 4;
  const int arow = tid >> 2, akq = (tid & 3) << 2;   // A: 4 consecutive k per thread
  const int bk = tid >> 4, bnq = (tid & 15) << 2;    // B: 4 consecutive n per thread
  const long abase = (long)seq[m0 + arow] * Hz;      // gathered embedding row

  float acc[4][4] = {};
  for (int k0 = 0; k0 < Hz; k0 += 16) {
    const float4 av = *(const float4*)(embed + abase + k0 + akq);
    const float4 bv = *(const float4*)(W1 + (long)(k0 + bk) * H2z + n0 + bnq);
    __syncthreads();
    As[akq + 0][arow] = av.x; As[akq + 1][arow] = av.y;
    As[akq + 2][arow] = av.z; As[akq + 3][arow] = av.w;
    *(float4*)&Bs[bk][bnq] = bv;
    __syncthreads();
#pragma unroll
    for (int kk = 0; kk < 16; ++kk) {
      float a[4], bb[4];
      *(float4*)a  = *(const float4*)&As[kk][ty << 2];
      *(float4*)bb = *(const float4*)&Bs[kk][tx << 2];
#pragma unroll
      for (int i = 0; i < 4; ++i)
#pragma unroll
        for (int j = 0; j < 4; ++j) acc[i][j] = fmaf(a[i], bb[j], acc[i][j]);
    }
  }
  const float4 bias = *(const float4*)(b1 + n0 + (tx << 2));
#pragma unroll
  for (int i = 0; i < 4; ++i) {
    float4 o;
    o.x = fmaxf(acc[i][0] + bias.x, 0.0f);
    o.y = fmaxf(acc[i][1] + bias.y, 0.0f);
    o.z = fmaxf(acc[i][2] + bias.z, 0.0f);
    o.w = fmaxf(acc[i][3] + bias.w, 0.0f);
    *(float4*)(y1 + (long)(m0 + (ty << 2) + i) * H2z + n0 + (tx << 2)) = o;
  }
}

// ---------------------------------------------------------------------------
// GEMM2: x[4096,256] = y1 @ W2[512,256] + b2 + embed[seq]  (residual fused)
// ---------------------------------------------------------------------------
__global__ __launch_bounds__(256) void k_gemm2(
    const int* __restrict__ seq, const float* __restrict__ embed,
    const float* __restrict__ y1, const float* __restrict__ W2,
    const float* __restrict__ b2, float* __restrict__ x)
{
  __shared__ float As[16][68];
  __shared__ float Bs[16][68];
  const int tid = threadIdx.x;
  const int n0 = blockIdx.x * 64, m0 = blockIdx.y * 64;
  const int tx = tid & 15, ty = tid >> 4;
  const int arow = tid >> 2, akq = (tid & 3) << 2;
  const int bk = tid >> 4, bnq = (tid & 15) << 2;
  const long abase = (long)(m0 + arow) * H2z;

  float acc[4][4] = {};
  for (int k0 = 0; k0 < H2z; k0 += 16) {
    const float4 av = *(const float4*)(y1 + abase + k0 + akq);
    const float4 bv = *(const float4*)(W2 + (long)(k0 + bk) * Hz + n0 + bnq);
    __syncthreads();
    As[akq + 0][arow] = av.x; As[akq + 1][arow] = av.y;
    As[akq + 2][arow] = av.z; As[akq + 3][arow] = av.w;
    *(float4*)&Bs[bk][bnq] = bv;
    __syncthreads();
#pragma unroll
    for (int kk = 0; kk < 16; ++kk) {
      float a[4], bb[4];
      *(float4*)a  = *(const float4*)&As[kk][ty << 2];
      *(float4*)bb = *(const float4*)&Bs[kk][tx << 2];
#pragma unroll
      for (int i = 0; i < 4; ++i)
#pragma unroll
        for (int j = 0; j < 4; ++j) acc[i][j] = fmaf(a[i], bb[j], acc[i][j]);
    }
  }
  const float4 bias = *(const float4*)(b2 + n0 + (tx << 2));
#pragma unroll
  for (int i = 0; i < 4; ++i) {
    const int row = m0 + (ty << 2) + i;
    const float4 ev = *(const float4*)(embed + (long)seq[row] * Hz + n0 + (tx << 2));
    float4 o;
    o.x = acc[i][0] + bias.x + ev.x;
    o.y = acc[i][1] + bias.y + ev.y;
    o.z = acc[i][2] + bias.z + ev.z;
    o.w = acc[i][3] + bias.w + ev.w;
    *(float4*)(x + (long)row * Hz + n0 + (tx << 2)) = o;
  }
}

// ---------------------------------------------------------------------------
// LayerNorm + L2-normalized copy. One wave per row, 4 elems/lane.
// ---------------------------------------------------------------------------
__global__ __launch_bounds__(256) void k_ln(
    const float* __restrict__ x, const float* __restrict__ gamma,
    const float* __restrict__ beta, float* __restrict__ h,
    float* __restrict__ hn)
{
  const int lane = threadIdx.x & 63;
  const long row = (long)blockIdx.x * 4 + (threadIdx.x >> 6);
  const int off = lane << 2;
  const float4 xv = *(const float4*)(x + row * Hz + off);
  float s  = xv.x + xv.y + xv.z + xv.w;
  float ss = xv.x * xv.x + xv.y * xv.y + xv.z * xv.z + xv.w * xv.w;
#pragma unroll
  for (int o = 32; o >= 1; o >>= 1) { s += __shfl_xor(s, o); ss += __shfl_xor(ss, o); }
  const float mu   = s * (1.0f / Hz);
  const float var  = ss * (1.0f / Hz) - mu * mu;
  const float rstd = rsqrtf(var + 1e-5f);
  const float4 gv = *(const float4*)(gamma + off);
  const float4 bv = *(const float4*)(beta + off);
  float4 hv;
  hv.x = (xv.x - mu) * rstd * gv.x + bv.x;
  hv.y = (xv.y - mu) * rstd * gv.y + bv.y;
  hv.z = (xv.z - mu) * rstd * gv.z + bv.z;
  hv.w = (xv.w - mu) * rstd * gv.w + bv.w;
  *(float4*)(h + row * Hz + off) = hv;
  float hs = hv.x * hv.x + hv.y * hv.y + hv.z * hv.z + hv.w * hv.w;
#pragma unroll
  for (int o = 32; o >= 1; o >>= 1) hs += __shfl_xor(hs, o);
  const float inv = 1.0f / fmaxf(sqrtf(hs), 1e-12f);
  float4 nv = {hv.x * inv, hv.y * inv, hv.z * inv, hv.w * inv};
  *(float4*)(hn + row * Hz + off) = nv;
}

// ---------------------------------------------------------------------------
// Delta-rule recurrence, reformulated backward on vectors (exact algebra):
//   u = q = h[:,511];  for t=510..0: d = kn_t.u;  m += c d k_t;  u -= c d kn_t
// One wave per batch, 4 elems/lane, depth-4 software prefetch.
// Also fuses r = m @ Wrp + brp.
// ---------------------------------------------------------------------------
__global__ __launch_bounds__(64) void k_recur(
    const float* __restrict__ h, const float* __restrict__ hn,
    const float* __restrict__ Wrp, const float* __restrict__ brp,
    float* __restrict__ r)
{
  const int b = blockIdx.x, lane = threadIdx.x;
  const float* hb  = h  + (long)b * Lz * Hz;
  const float* hnb = hn + (long)b * Lz * Hz;
  const int off = lane << 2;
  float4 u = *(const float4*)(hb + 511 * Hz + off);
  float4 m = {0.0f, 0.0f, 0.0f, 0.0f};
  float4 kbuf[4], nbuf[4];
#pragma unroll
  for (int j = 0; j < 4; ++j) {
    nbuf[j] = *(const float4*)(hnb + (510 - j) * Hz + off);
    kbuf[j] = *(const float4*)(hb  + (510 - j) * Hz + off);
  }
  for (int tb = 510; tb >= 6; tb -= 4) {   // 127 chunks: t = 510..3
#pragma unroll
    for (int j = 0; j < 4; ++j) {
      const float4 kn = nbuf[j], kv = kbuf[j];
      int tp = tb - j - 4; if (tp < 0) tp = 0;   // clamp: dummy load, never used
      nbuf[j] = *(const float4*)(hnb + tp * Hz + off);
      kbuf[j] = *(const float4*)(hb  + tp * Hz + off);
      float p = kn.x * u.x + kn.y * u.y + kn.z * u.z + kn.w * u.w;
#pragma unroll
      for (int s = 32; s >= 1; s >>= 1) p += __shfl_xor(p, s);
      const float cd = CF * p;
      m.x = fmaf(cd, kv.x, m.x); m.y = fmaf(cd, kv.y, m.y);
      m.z = fmaf(cd, kv.z, m.z); m.w = fmaf(cd, kv.w, m.w);
      u.x = fmaf(-cd, kn.x, u.x); u.y = fmaf(-cd, kn.y, u.y);
      u.z = fmaf(-cd, kn.z, u.z); u.w = fmaf(-cd, kn.w, u.w);
    }
  }
#pragma unroll
  for (int j = 0; j < 3; ++j) {            // epilogue: t = 2, 1, 0
    const float4 kn = nbuf[j], kv = kbuf[j];
    float p = kn.x * u.x + kn.y * u.y + kn.z * u.z + kn.w * u.w;
#pragma unroll
    for (int s = 32; s >= 1; s >>= 1) p += __shfl_xor(p, s);
    const float cd = CF * p;
    m.x = fmaf(cd, kv.x, m.x); m.y = fmaf(cd, kv.y, m.y);
    m.z = fmaf(cd, kv.z, m.z); m.w = fmaf(cd, kv.w, m.w);
    u.x = fmaf(-cd, kn.x, u.x); u.y = fmaf(-cd, kn.y, u.y);
    u.z = fmaf(-cd, kn.z, u.z); u.w = fmaf(-cd, kn.w, u.w);
  }
  // r[b] = m @ Wrp + brp.  lane holds m[4*lane .. 4*lane+3]; cols {lane+64*cc}.
  float racc[4] = {0.0f, 0.0f, 0.0f, 0.0f};
  for (int j = 0; j < 64; ++j) {
    float4 mj;
    mj.x = __shfl(m.x, j); mj.y = __shfl(m.y, j);
    mj.z = __shfl(m.z, j); mj.w = __shfl(m.w, j);
    const float mv[4] = {mj.x, mj.y, mj.z, mj.w};
#pragma unroll
    for (int c = 0; c < 4; ++c) {
      const long i = (long)j * 4 + c;
#pragma unroll
      for (int cc = 0; cc < 4; ++cc)
        racc[cc] = fmaf(mv[c], Wrp[i * Hz + cc * 64 + lane], racc[cc]);
    }
  }
#pragma unroll
  for (int cc = 0; cc < 4; ++cc)
    r[b * Hz + cc * 64 + lane] = racc[cc] + brp[cc * 64 + lane];
}

// ---------------------------------------------------------------------------
// out[8,32000] = r[8,256] @ Wout[256,32000] + bout.  One thread per column.
// ---------------------------------------------------------------------------
__global__ __launch_bounds__(256) void k_outproj(
    const float* __restrict__ r, const float* __restrict__ Wout,
    const float* __restrict__ bout, float* __restrict__ out)
{
  __shared__ float rs[Hz][8];   // [i][b] layout -> 2x float4 broadcast per i
  const int tid = threadIdx.x;
  for (int idx = tid; idx < 8 * Hz; idx += 256) {
    const int bb = idx >> 8, i = idx & 255;
    rs[i][bb] = r[idx];
  }
  __syncthreads();
  const int v = blockIdx.x * 256 + tid;
  float acc[8] = {};
#pragma unroll 8
  for (int i = 0; i < Hz; ++i) {
    const float w = Wout[(long)i * Vz + v];
    const float4 r0 = *(const float4*)&rs[i][0];
    const float4 r1 = *(const float4*)&rs[i][4];
    acc[0] = fmaf(r0.x, w, acc[0]); acc[1] = fmaf(r0.y, w, acc[1]);
    acc[2] = fmaf(r0.z, w, acc[2]); acc[3] = fmaf(r0.w, w, acc[3]);
    acc[4] = fmaf(r1.x, w, acc[4]); acc[5] = fmaf(r1.y, w, acc[5]);
    acc[6] = fmaf(r1.z, w, acc[6]); acc[7] = fmaf(r1.w, w, acc[7]);
  }
  const float bo = bout[v];
#pragma unroll
  for (int bb = 0; bb < 8; ++bb) out[(long)bb * Vz + v] = acc[bb] + bo;
}

// ---------------------------------------------------------------------------
extern "C" void kernel_launch(void* const* d_in, const int* in_sizes, int n_in,
                              void* d_out, int out_size, void* d_ws, size_t ws_size,
                              hipStream_t stream)
{
  const int*   seq   = (const int*)  d_in[0];
  const float* embed = (const float*)d_in[1];
  const float* W1    = (const float*)d_in[2];
  const float* b1    = (const float*)d_in[3];
  const float* W2    = (const float*)d_in[4];
  const float* b2    = (const float*)d_in[5];
  const float* gamma = (const float*)d_in[6];
  const float* beta  = (const float*)d_in[7];
  const float* Wrp   = (const float*)d_in[8];
  const float* brp   = (const float*)d_in[9];
  const float* Wout  = (const float*)d_in[10];
  const float* bout  = (const float*)d_in[11];
  float* out = (float*)d_out;

  char* ws = (char*)d_ws;
  float* y1 = (float*)ws;                                   // 4096*512 f32 = 8 MB
  float* xb = (float*)(ws + (size_t)Mz * H2z * 4);          // 4096*256 f32 = 4 MB
  float* hb = (float*)(ws + (size_t)Mz * H2z * 4 + (size_t)Mz * Hz * 4);
  float* hnb = (float*)(ws + (size_t)Mz * H2z * 4 + 2 * (size_t)Mz * Hz * 4);
  float* rb  = (float*)(ws + (size_t)Mz * H2z * 4 + 3 * (size_t)Mz * Hz * 4);

  k_gemm1<<<dim3(H2z / 64, Mz / 64), 256, 0, stream>>>(seq, embed, W1, b1, y1);
  k_gemm2<<<dim3(Hz / 64, Mz / 64), 256, 0, stream>>>(seq, embed, y1, W2, b2, xb);
  k_ln<<<Mz / 4, 256, 0, stream>>>(xb, gamma, beta, hb, hnb);
  k_recur<<<Bz, 64, 0, stream>>>(hb, hnb, Wrp, brp, rb);
  k_outproj<<<Vz / 256, 256, 0, stream>>>(rb, Wout, bout, out);
}